// Round 7
// baseline (721.977 us; speedup 1.0000x reference)
//
#include <hip/hip_runtime.h>
#include <stdint.h>

typedef __attribute__((ext_vector_type(8))) short bf16x8;   // 8 bf16 = 4 VGPRs
typedef __attribute__((ext_vector_type(4))) float f32x4;

#define NBLK 256            // edge-chunk blocks for the deterministic counting sort
#define BSH  7              // bucket = 128 nodes
#define BSZ  128
#define RNG  13             // src ranges of 4096 nodes (4096*512B = 2MB, fits XCD L2)
#define NPN  13             // nodes per wave in k_agg

typedef __attribute__((address_space(1))) const unsigned int gu32;
typedef __attribute__((address_space(3))) unsigned int lu32;

__device__ __forceinline__ float bf2f(unsigned short b) {
    union { unsigned u; float f; } c; c.u = ((unsigned)b) << 16; return c.f;
}
__device__ __forceinline__ float bflo(unsigned w) {
    union { unsigned u; float f; } c; c.u = w << 16; return c.f;
}
__device__ __forceinline__ float bfhi(unsigned w) {
    union { unsigned u; float f; } c; c.u = w & 0xffff0000u; return c.f;
}
__device__ __forceinline__ unsigned short f2bf(float f) {
    union { float f; unsigned u; } c; c.f = f;
    unsigned u = c.u;
    u += 0x7fffu + ((u >> 16) & 1u);          // round-to-nearest-even
    return (unsigned short)(u >> 16);
}

__global__ void GNNEncoder_317827579954_kernel() {}

// flags[0] = 1 if dense inputs are f32 (else bf16); flags[1] = 1 if edge_index is int64.
__global__ void k_flags(const unsigned* __restrict__ x, const int* __restrict__ ei,
                        int E, int* __restrict__ flags) {
    int t = threadIdx.x;              // 0..63
    int pl = 0;
    for (int i = t; i < 256; i += 64) {
        unsigned u = x[i] & 0xffffu;
        unsigned e = (u >> 7) & 0xffu;
        if ((e >= 100u && e <= 145u) || u == 0u) ++pl;
    }
    for (int off = 32; off; off >>= 1) pl += __shfl_down(pl, off);
    int n = E < 64 ? E : 64;
    unsigned long long nz = __ballot(t < n ? (ei[2 * t + 1] != 0) : 0);
    if (t == 0) {
        flags[0] = (pl >= 192) ? 0 : 1;       // 0 = bf16, 1 = f32
        flags[1] = (nz == 0ull) ? 1 : 0;      // 1 = int64
    }
}

// Both weights: W [k][n] (raw dtype) -> Wt [n][k] bf16 (256x256). blockIdx < 256 -> W1.
__global__ void k_cvtT(const void* __restrict__ Wa, unsigned short* __restrict__ Wta,
                       const void* __restrict__ Wb, unsigned short* __restrict__ Wtb,
                       const int* __restrict__ flags) {
    int bb = blockIdx.x;
    const void* W = bb < 256 ? Wa : Wb;
    unsigned short* Wt = bb < 256 ? Wta : Wtb;
    int n = bb & 255, k = threadIdx.x;
    unsigned short v;
    if (flags[0]) v = f2bf(((const float*)W)[k * 256 + n]);
    else          v = ((const unsigned short*)W)[k * 256 + n];
    Wt[n * 256 + k] = v;
}

// ---- deterministic two-level counting-sort CSR build (ZERO global atomics) ----

__global__ __launch_bounds__(256) void k_cmat(const int* __restrict__ ei, int E,
                                              const int* __restrict__ flags,
                                              int* __restrict__ cmat, int nb) {
    __shared__ int lc[512];
    int t = threadIdx.x, b = blockIdx.x;
    for (int i = t; i < nb; i += 256) lc[i] = 0;
    __syncthreads();
    int chunk = (E + NBLK - 1) / NBLK;
    int beg = b * chunk;
    int end = beg + chunk; if (end > E) end = E;
    int i64 = flags[1];
    for (int i = beg + t; i < end; i += 256) {
        int d = i64 ? ei[2 * E + 2 * i] : ei[E + i];
        atomicAdd(&lc[d >> BSH], 1);
    }
    __syncthreads();
    for (int j = t; j < nb; j += 256) cmat[j * NBLK + b] = lc[j];
}

__global__ __launch_bounds__(512) void k_cscan(int* __restrict__ cmat,
                                               int* __restrict__ boff,
                                               int* __restrict__ noffs,
                                               int nb, int N, int E) {
    __shared__ int sc[512];
    int t = threadIdx.x;
    int run = 0;
    if (t < nb) {
        int* row = cmat + t * NBLK;
        for (int b = 0; b < NBLK; ++b) { int v = row[b]; row[b] = run; run += v; }
    }
    sc[t] = run;                       // bucket total (0 for t >= nb)
    __syncthreads();
    int val = run;
    for (int off = 1; off < 512; off <<= 1) {
        int u = (t >= off) ? sc[t - off] : 0;
        __syncthreads();
        sc[t] += u;
        __syncthreads();
    }
    int ex = sc[t] - val;              // exclusive prefix of bucket totals
    if (t < nb) {
        boff[t] = ex;
        int* row = cmat + t * NBLK;
        for (int b = 0; b < NBLK; ++b) row[b] += ex;
    }
    if (t == 0) { boff[nb] = E; noffs[(size_t)N * RNG] = E; }
}

__global__ __launch_bounds__(256) void k_fillmat(const int* __restrict__ ei, int E,
                                                 const int* __restrict__ flags,
                                                 const int* __restrict__ cmat,
                                                 unsigned* __restrict__ tmp, int nb) {
    __shared__ int cur[512];
    int t = threadIdx.x, b = blockIdx.x;
    for (int j = t; j < nb; j += 256) cur[j] = cmat[j * NBLK + b];
    __syncthreads();
    int chunk = (E + NBLK - 1) / NBLK;
    int beg = b * chunk;
    int end = beg + chunk; if (end > E) end = E;
    int i64 = flags[1];
    for (int i = beg + t; i < end; i += 256) {
        int s, d;
        if (i64) { s = ei[2 * i]; d = ei[2 * E + 2 * i]; }
        else     { s = ei[i];     d = ei[E + i]; }
        int p = atomicAdd(&cur[d >> BSH], 1);        // LDS atomic only
        tmp[p] = ((unsigned)s << BSH) | (unsigned)(d & (BSZ - 1));
    }
}

// Per-bucket: LDS (node,src-range) key count + scan -> noffs segments, dinv,
// then key-sorted CSR fill. Key = dst_local*16 + (src>>12); ranges 13..15 empty.
__global__ __launch_bounds__(256) void k_bbuild(const unsigned* __restrict__ tmp,
                                                const int* __restrict__ boff,
                                                int* __restrict__ noffs,
                                                float* __restrict__ dinv,
                                                int* __restrict__ csr, int N) {
    __shared__ int kc[2048];
    __shared__ int cur[2048];
    __shared__ int sc[256];
    __shared__ int tot;
    int b = blockIdx.x;
    int t = threadIdx.x;
    int base = b << BSH;
    int beg = boff[b], end = boff[b + 1];
    for (int i = t; i < 2048; i += 256) kc[i] = 0;
    __syncthreads();
    for (int i = beg + t; i < end; i += 256) {
        unsigned u = tmp[i];
        atomicAdd(&kc[(u & 127u) * 16 + (u >> 19)], 1);   // u>>19 = src>>12
    }
    __syncthreads();
    // exclusive scan over 2048 keys: 8 per thread + block scan
    int b8 = t * 8, loc[8], msum = 0;
#pragma unroll
    for (int j = 0; j < 8; ++j) { loc[j] = kc[b8 + j]; msum += loc[j]; }
    sc[t] = msum;
    __syncthreads();
    int val = msum;
    for (int off = 1; off < 256; off <<= 1) {
        int u2 = (t >= off) ? sc[t - off] : 0;
        __syncthreads();
        sc[t] += u2;
        __syncthreads();
    }
    int run = sc[t] - val;
    if (t == 255) tot = sc[255];
#pragma unroll
    for (int j = 0; j < 8; ++j) { int v2 = loc[j]; kc[b8 + j] = run; cur[b8 + j] = run; run += v2; }
    __syncthreads();
    // per-node segment starts + dinv
    for (int i = t; i < 128 * RNG; i += 256) {
        int local = i / RNG, o = i - local * RNG;
        int v = base + local;
        if (v < N) noffs[(size_t)v * RNG + o] = beg + kc[local * 16 + o];
    }
    if (t < 128) {
        int v = base + t;
        if (v < N) {
            int s0 = kc[t * 16];
            int s1 = (t == 127) ? tot : kc[(t + 1) * 16];
            dinv[v] = rsqrtf((float)(s1 - s0 + 1));   // +1 = self loop
        }
    }
    __syncthreads();
    // key-sorted fill (node-major, src-range-minor)
    for (int i = beg + t; i < end; i += 256) {
        unsigned u = tmp[i];
        int p = atomicAdd(&cur[(u & 127u) * 16 + (u >> 19)], 1);
        csr[beg + p] = (int)(u >> BSH);
    }
}

// C[M,256] = dinv[row] * (A[M,256] @ Bt^T), A in f32 (converted in-flight) or bf16.
// B K-slices double-buffered in LDS via global_load_lds (16 B, XOR-swizzled chunks);
// C staged through the same LDS for fully-coalesced uint4 stores.
__global__ __launch_bounds__(256) void k_gemm(const void* __restrict__ Araw,
                                              const unsigned short* __restrict__ Bt,
                                              unsigned short* __restrict__ C,
                                              const float* __restrict__ dinv,
                                              const int* __restrict__ flags, int useflag,
                                              int M) {
    __shared__ unsigned short smem[16384];   // 32 KB: B dbuf 2x16KB, then C 64x256 tile
    int tid  = threadIdx.x;
    int lane = tid & 63;
    int wave = tid >> 6;
    int q = lane >> 4;
    int r = lane & 15;
    int rowBase0 = blockIdx.x * 64;
    int rowBase = rowBase0 + wave * 16;
    int af32 = useflag ? flags[0] : 0;       // wave-uniform branch

    int arow = rowBase + r;
    arow = arow < M ? arow : M - 1;
    const unsigned short* aptrh = (const unsigned short*)Araw + (size_t)arow * 256;
    const float*          aptrf = (const float*)Araw + (size_t)arow * 256;

    auto stage = [&](int buf, int kk) {
#pragma unroll
        for (int j = 0; j < 4; ++j) {
            int c = wave * 256 + j * 64 + lane;
            int col = c >> 2;
            int kc = (c & 3) ^ (col & 3);
            const unsigned short* src = Bt + col * 256 + kk + kc * 8;
            unsigned short* dst = smem + buf * 8192 + (wave * 4 + j) * 512;
            __builtin_amdgcn_global_load_lds((gu32*)src, (lu32*)dst, 16, 0, 0);
        }
    };

    stage(0, 0);
    __syncthreads();                         // vmcnt(0) drain: buf0 ready

    f32x4 acc[16] = {};
    int cur = 0;
    for (int kk = 0; kk < 256; kk += 32) {
        if (kk < 224) stage(cur ^ 1, kk + 32);   // prefetch next slice first (T3)
        bf16x8 a;
        if (af32) {
            float4 v0 = *(const float4*)(aptrf + kk + q * 8);
            float4 v1 = *(const float4*)(aptrf + kk + q * 8 + 4);
            union { unsigned short s[8]; bf16x8 v; } ua;
            ua.s[0] = f2bf(v0.x); ua.s[1] = f2bf(v0.y); ua.s[2] = f2bf(v0.z); ua.s[3] = f2bf(v0.w);
            ua.s[4] = f2bf(v1.x); ua.s[5] = f2bf(v1.y); ua.s[6] = f2bf(v1.z); ua.s[7] = f2bf(v1.w);
            a = ua.v;
        } else {
            a = *(const bf16x8*)(aptrh + kk + q * 8);
        }
#pragma unroll
        for (int nt = 0; nt < 16; ++nt) {
            int col = nt * 16 + r;
            const unsigned short* bp = smem + cur * 8192 + col * 32 + (q ^ (col & 3)) * 8;
            bf16x8 b = *(const bf16x8*)bp;
            acc[nt] = __builtin_amdgcn_mfma_f32_16x16x32_bf16(a, b, acc[nt], 0, 0, 0);
        }
        __syncthreads();                     // drains next-slice loads; guards buf reuse
        cur ^= 1;
    }

    // epilogue: reuse smem as 64x256 bf16 C tile
    float ds4[4];
#pragma unroll
    for (int r2 = 0; r2 < 4; ++r2) {
        int row = rowBase + q * 4 + r2;
        ds4[r2] = (row < M) ? dinv[row] : 0.f;
    }
    int lrow0 = wave * 16 + q * 4;
#pragma unroll
    for (int nt = 0; nt < 16; ++nt) {
        int col = nt * 16 + r;
#pragma unroll
        for (int r2 = 0; r2 < 4; ++r2)
            smem[(lrow0 + r2) * 256 + col] = f2bf(acc[nt][r2] * ds4[r2]);
    }
    __syncthreads();
#pragma unroll
    for (int p = 0; p < 8; ++p) {
        int idx = wave * 4096 + p * 512 + lane * 8;   // in shorts
        int grow = rowBase0 + (idx >> 8);
        if (grow < M)
            *(uint4*)(C + (size_t)grow * 256 + (idx & 255)) = *(const uint4*)(smem + idx);
    }
}

// Range-phased row-sum aggregation over dinv-prescaled rows XWs.
// One wave owns NPN consecutive nodes; lane owns 4 channels (uint2 = 8 B).
// Outer loop over 13 src-ranges (2 MB each): all co-resident waves gather from
// the same L2-resident range -> L2-miss traffic collapses.
__global__ __launch_bounds__(256, 4) void k_agg(const unsigned short* __restrict__ XWs,
                                                const int* __restrict__ csr,
                                                const int* __restrict__ noffs,
                                                const float* __restrict__ dinv,
                                                const void* __restrict__ bias,
                                                void* __restrict__ out,
                                                int relu, int final_,
                                                const int* __restrict__ flags, int N) {
    int wgid = blockIdx.x * 4 + (threadIdx.x >> 6);
    int v0 = wgid * NPN;
    int lane = threadIdx.x & 63;
    int c = lane * 4;                 // 4 channels, 8 B
    float acc[NPN][4];
#pragma unroll
    for (int n = 0; n < NPN; ++n) { acc[n][0] = acc[n][1] = acc[n][2] = acc[n][3] = 0.f; }

    for (int o = 0; o < RNG; ++o) {
#pragma unroll
        for (int n = 0; n < NPN; ++n) {
            int v = v0 + n;
            if (v >= N) continue;                    // wave-uniform
            size_t idx = (size_t)v * RNG + o;
            int e   = noffs[idx];
            int end = noffs[idx + 1];
            for (; e + 4 <= end; e += 4) {
                int s0 = csr[e], s1 = csr[e + 1], s2 = csr[e + 2], s3 = csr[e + 3];
                uint2 u0 = *(const uint2*)(XWs + (size_t)s0 * 256 + c);
                uint2 u1 = *(const uint2*)(XWs + (size_t)s1 * 256 + c);
                uint2 u2 = *(const uint2*)(XWs + (size_t)s2 * 256 + c);
                uint2 u3 = *(const uint2*)(XWs + (size_t)s3 * 256 + c);
                acc[n][0] += bflo(u0.x); acc[n][1] += bfhi(u0.x);
                acc[n][2] += bflo(u0.y); acc[n][3] += bfhi(u0.y);
                acc[n][0] += bflo(u1.x); acc[n][1] += bfhi(u1.x);
                acc[n][2] += bflo(u1.y); acc[n][3] += bfhi(u1.y);
                acc[n][0] += bflo(u2.x); acc[n][1] += bfhi(u2.x);
                acc[n][2] += bflo(u2.y); acc[n][3] += bfhi(u2.y);
                acc[n][0] += bflo(u3.x); acc[n][1] += bfhi(u3.x);
                acc[n][2] += bflo(u3.y); acc[n][3] += bfhi(u3.y);
            }
            for (; e < end; ++e) {
                int s = csr[e];
                uint2 u = *(const uint2*)(XWs + (size_t)s * 256 + c);
                acc[n][0] += bflo(u.x); acc[n][1] += bfhi(u.x);
                acc[n][2] += bflo(u.y); acc[n][3] += bfhi(u.y);
            }
        }
    }

    // bias (per-channel, hoisted)
    float bb[4];
    if (flags[0]) {
        float4 b0 = *(const float4*)((const float*)bias + c);
        bb[0] = b0.x; bb[1] = b0.y; bb[2] = b0.z; bb[3] = b0.w;
    } else {
        uint2 bu = *(const uint2*)((const unsigned short*)bias + c);
        bb[0] = bflo(bu.x); bb[1] = bfhi(bu.x);
        bb[2] = bflo(bu.y); bb[3] = bfhi(bu.y);
    }
    int f32out = final_ && flags[0];
#pragma unroll
    for (int n = 0; n < NPN; ++n) {
        int v = v0 + n;
        if (v >= N) continue;
        float dv = dinv[v];
        uint2 su = *(const uint2*)(XWs + (size_t)v * 256 + c);   // self (prescaled)
        float r0 = dv * (acc[n][0] + bflo(su.x)) + bb[0];
        float r1 = dv * (acc[n][1] + bfhi(su.x)) + bb[1];
        float r2 = dv * (acc[n][2] + bflo(su.y)) + bb[2];
        float r3 = dv * (acc[n][3] + bfhi(su.y)) + bb[3];
        if (relu) {
            r0 = fmaxf(r0, 0.f); r1 = fmaxf(r1, 0.f);
            r2 = fmaxf(r2, 0.f); r3 = fmaxf(r3, 0.f);
        }
        if (f32out) {
            float4 o4; o4.x = r0; o4.y = r1; o4.z = r2; o4.w = r3;
            *(float4*)((float*)out + (size_t)v * 256 + c) = o4;
        } else {
            uint2 o2;
            o2.x = (unsigned)f2bf(r0) | ((unsigned)f2bf(r1) << 16);
            o2.y = (unsigned)f2bf(r2) | ((unsigned)f2bf(r3) << 16);
            *(uint2*)((unsigned short*)out + (size_t)v * 256 + c) = o2;
        }
    }
}

extern "C" void kernel_launch(void* const* d_in, const int* in_sizes, int n_in,
                              void* d_out, int out_size, void* d_ws, size_t ws_size,
                              hipStream_t stream) {
    (void)n_in; (void)out_size; (void)ws_size;
    const void* x  = d_in[0];
    const int*  ei = (const int*)d_in[1];
    const void* W1 = d_in[2];
    const void* b1 = d_in[3];
    const void* W2 = d_in[4];
    const void* b2 = d_in[5];

    int N = in_sizes[0] / 256;          // 50000
    int E = in_sizes[1] / 2;            // 1600000
    int NB = (N + BSZ - 1) / BSZ;       // 391 buckets of 128 nodes

    char* p = (char*)d_ws;
    auto alloc = [&](size_t bytes) {
        char* r = p;
        p += (bytes + 255) & ~(size_t)255;
        return r;
    };
    int*            flags  = (int*)alloc(8);
    int*            boff   = (int*)alloc(516 * 4);
    int*            noffs  = (int*)alloc(((size_t)N * RNG + 16) * 4);   // 2.6 MB
    float*          dinv   = (float*)alloc((size_t)N * 4);
    unsigned short* wt1    = (unsigned short*)alloc(256 * 256 * 2);
    unsigned short* wt2    = (unsigned short*)alloc(256 * 256 * 2);
    int*            csr    = (int*)alloc((size_t)E * 4);
    unsigned short* buf0   = (unsigned short*)alloc((size_t)N * 256 * 2);
    unsigned short* buf1   = (unsigned short*)alloc((size_t)N * 256 * 2);
    unsigned*       tmp    = (unsigned*)buf1;   // dead until gemm2 writes buf1
    int*            cmat   = (int*)buf0;        // dead until k_agg1 writes buf0
    unsigned short* xw1    = (unsigned short*)d_out;  // layer-1 XW scratch in d_out

    k_flags<<<1, 64, 0, stream>>>((const unsigned*)x, ei, E, flags);
    k_cmat<<<NBLK, 256, 0, stream>>>(ei, E, flags, cmat, NB);
    k_cscan<<<1, 512, 0, stream>>>(cmat, boff, noffs, NB, N, E);
    k_fillmat<<<NBLK, 256, 0, stream>>>(ei, E, flags, cmat, tmp, NB);
    k_bbuild<<<NB, 256, 0, stream>>>(tmp, boff, noffs, dinv, csr, N);

    k_cvtT<<<512, 256, 0, stream>>>(W1, wt1, W2, wt2, flags);

    int gAgg = (N + 4 * NPN - 1) / (4 * NPN);   // 962 blocks, all co-resident
    k_gemm<<<(N + 63) / 64, 256, 0, stream>>>(x, wt1, xw1, dinv, flags, 1, N);   // dinv*(X@W1)
    k_agg<<<gAgg, 256, 0, stream>>>(xw1, csr, noffs, dinv, b1,
                                    (void*)buf0, 1, 0, flags, N);                // h -> buf0
    k_gemm<<<(N + 63) / 64, 256, 0, stream>>>(buf0, wt2, buf1, dinv, flags, 0, N); // dinv*(H@W2)
    k_agg<<<gAgg, 256, 0, stream>>>(buf1, csr, noffs, dinv, b2,
                                    d_out, 0, 1, flags, N);                      // final
}

// Round 8
// 471.403 us; speedup vs baseline: 1.5315x; 1.5315x over previous
//
#include <hip/hip_runtime.h>
#include <stdint.h>

typedef __attribute__((ext_vector_type(8))) short bf16x8;   // 8 bf16 = 4 VGPRs
typedef __attribute__((ext_vector_type(4))) float f32x4;

#define NBLK 256            // edge-chunk blocks for the deterministic counting sort
#define BSH  7              // bucket = 128 nodes
#define BSZ  128

typedef __attribute__((address_space(1))) const unsigned int gu32;
typedef __attribute__((address_space(3))) unsigned int lu32;

__device__ __forceinline__ float bf2f(unsigned short b) {
    union { unsigned u; float f; } c; c.u = ((unsigned)b) << 16; return c.f;
}
__device__ __forceinline__ float bflo(unsigned w) {
    union { unsigned u; float f; } c; c.u = w << 16; return c.f;
}
__device__ __forceinline__ float bfhi(unsigned w) {
    union { unsigned u; float f; } c; c.u = w & 0xffff0000u; return c.f;
}
__device__ __forceinline__ unsigned short f2bf(float f) {
    union { float f; unsigned u; } c; c.f = f;
    unsigned u = c.u;
    u += 0x7fffu + ((u >> 16) & 1u);          // round-to-nearest-even
    return (unsigned short)(u >> 16);
}

__global__ void GNNEncoder_317827579954_kernel() {}

// flags[0] = 1 if dense inputs are f32 (else bf16); flags[1] = 1 if edge_index is int64.
__global__ void k_flags(const unsigned* __restrict__ x, const int* __restrict__ ei,
                        int E, int* __restrict__ flags) {
    int t = threadIdx.x;              // 0..63
    int pl = 0;
    for (int i = t; i < 256; i += 64) {
        unsigned u = x[i] & 0xffffu;
        unsigned e = (u >> 7) & 0xffu;
        if ((e >= 100u && e <= 145u) || u == 0u) ++pl;
    }
    for (int off = 32; off; off >>= 1) pl += __shfl_down(pl, off);
    int n = E < 64 ? E : 64;
    unsigned long long nz = __ballot(t < n ? (ei[2 * t + 1] != 0) : 0);
    if (t == 0) {
        flags[0] = (pl >= 192) ? 0 : 1;       // 0 = bf16, 1 = f32
        flags[1] = (nz == 0ull) ? 1 : 0;      // 1 = int64
    }
}

// Both weights: W [k][n] (raw dtype) -> Wt [n][k] bf16 (256x256). blockIdx < 256 -> W1.
__global__ void k_cvtT(const void* __restrict__ Wa, unsigned short* __restrict__ Wta,
                       const void* __restrict__ Wb, unsigned short* __restrict__ Wtb,
                       const int* __restrict__ flags) {
    int bb = blockIdx.x;
    const void* W = bb < 256 ? Wa : Wb;
    unsigned short* Wt = bb < 256 ? Wta : Wtb;
    int n = bb & 255, k = threadIdx.x;
    unsigned short v;
    if (flags[0]) v = f2bf(((const float*)W)[k * 256 + n]);
    else          v = ((const unsigned short*)W)[k * 256 + n];
    Wt[n * 256 + k] = v;
}

// ---- deterministic two-level counting-sort CSR build (ZERO global atomics) ----

__global__ __launch_bounds__(256) void k_cmat(const int* __restrict__ ei, int E,
                                              const int* __restrict__ flags,
                                              int* __restrict__ cmat, int nb) {
    __shared__ int lc[512];
    int t = threadIdx.x, b = blockIdx.x;
    for (int i = t; i < nb; i += 256) lc[i] = 0;
    __syncthreads();
    int chunk = (E + NBLK - 1) / NBLK;
    int beg = b * chunk;
    int end = beg + chunk; if (end > E) end = E;
    int i64 = flags[1];
    for (int i = beg + t; i < end; i += 256) {
        int d = i64 ? ei[2 * E + 2 * i] : ei[E + i];
        atomicAdd(&lc[d >> BSH], 1);
    }
    __syncthreads();
    for (int j = t; j < nb; j += 256) cmat[j * NBLK + b] = lc[j];
}

__global__ __launch_bounds__(512) void k_cscan(int* __restrict__ cmat,
                                               int* __restrict__ boff,
                                               int* __restrict__ offs,
                                               int nb, int N, int E) {
    __shared__ int sc[512];
    int t = threadIdx.x;
    int run = 0;
    if (t < nb) {
        int* row = cmat + t * NBLK;
        for (int b = 0; b < NBLK; ++b) { int v = row[b]; row[b] = run; run += v; }
    }
    sc[t] = run;                       // bucket total (0 for t >= nb)
    __syncthreads();
    int val = run;
    for (int off = 1; off < 512; off <<= 1) {
        int u = (t >= off) ? sc[t - off] : 0;
        __syncthreads();
        sc[t] += u;
        __syncthreads();
    }
    int ex = sc[t] - val;              // exclusive prefix of bucket totals
    if (t < nb) {
        boff[t] = ex;
        int* row = cmat + t * NBLK;
        for (int b = 0; b < NBLK; ++b) row[b] += ex;
    }
    if (t == 0) { boff[nb] = E; offs[N] = E; }
}

__global__ __launch_bounds__(256) void k_fillmat(const int* __restrict__ ei, int E,
                                                 const int* __restrict__ flags,
                                                 const int* __restrict__ cmat,
                                                 unsigned* __restrict__ tmp, int nb) {
    __shared__ int cur[512];
    int t = threadIdx.x, b = blockIdx.x;
    for (int j = t; j < nb; j += 256) cur[j] = cmat[j * NBLK + b];
    __syncthreads();
    int chunk = (E + NBLK - 1) / NBLK;
    int beg = b * chunk;
    int end = beg + chunk; if (end > E) end = E;
    int i64 = flags[1];
    for (int i = beg + t; i < end; i += 256) {
        int s, d;
        if (i64) { s = ei[2 * i]; d = ei[2 * E + 2 * i]; }
        else     { s = ei[i];     d = ei[E + i]; }
        int p = atomicAdd(&cur[d >> BSH], 1);        // LDS atomic only
        tmp[p] = ((unsigned)s << BSH) | (unsigned)(d & (BSZ - 1));
    }
}

// Per-bucket: LDS (node, src-range) key count + scan -> offs, dinv, then key-sorted
// CSR fill. Key = dst_local*16 + (src>>12): each node's edge list comes out sorted
// by ascending src range. Co-resident k_agg waves therefore sweep the XW array
// front-to-back roughly in lockstep ("soft phasing") -> L2-resident hot range.
__global__ __launch_bounds__(256) void k_bbuild(const unsigned* __restrict__ tmp,
                                                const int* __restrict__ boff,
                                                int* __restrict__ offs,
                                                float* __restrict__ dinv,
                                                int* __restrict__ csr, int N) {
    __shared__ int kc[2048];
    __shared__ int cur[2048];
    __shared__ int sc[256];
    __shared__ int tot;
    int b = blockIdx.x;
    int t = threadIdx.x;
    int base = b << BSH;
    int beg = boff[b], end = boff[b + 1];
    for (int i = t; i < 2048; i += 256) kc[i] = 0;
    __syncthreads();
    for (int i = beg + t; i < end; i += 256) {
        unsigned u = tmp[i];
        atomicAdd(&kc[(u & 127u) * 16 + (u >> 19)], 1);   // u>>19 = src>>12
    }
    __syncthreads();
    // exclusive scan over 2048 keys: 8 per thread + block scan
    int b8 = t * 8, loc[8], msum = 0;
#pragma unroll
    for (int j = 0; j < 8; ++j) { loc[j] = kc[b8 + j]; msum += loc[j]; }
    sc[t] = msum;
    __syncthreads();
    int val = msum;
    for (int off = 1; off < 256; off <<= 1) {
        int u2 = (t >= off) ? sc[t - off] : 0;
        __syncthreads();
        sc[t] += u2;
        __syncthreads();
    }
    int run = sc[t] - val;
    if (t == 255) tot = sc[255];
#pragma unroll
    for (int j = 0; j < 8; ++j) { int v2 = loc[j]; kc[b8 + j] = run; cur[b8 + j] = run; run += v2; }
    __syncthreads();
    if (t < 128) {
        int v = base + t;
        if (v < N) {
            int s0 = kc[t * 16];
            int s1 = (t == 127) ? tot : kc[(t + 1) * 16];
            offs[v] = beg + s0;
            dinv[v] = rsqrtf((float)(s1 - s0 + 1));   // +1 = self loop
        }
    }
    __syncthreads();
    // key-sorted fill (node-major, src-range-minor)
    for (int i = beg + t; i < end; i += 256) {
        unsigned u = tmp[i];
        int p = atomicAdd(&cur[(u & 127u) * 16 + (u >> 19)], 1);
        csr[beg + p] = (int)(u >> BSH);
    }
}

// C[M,256] = dinv[row] * (A[M,256] @ Bt^T), A in f32 (converted in-flight) or bf16.
// B K-slices double-buffered in LDS via global_load_lds (16 B, XOR-swizzled chunks);
// C staged through the same LDS for fully-coalesced uint4 stores.
__global__ __launch_bounds__(256) void k_gemm(const void* __restrict__ Araw,
                                              const unsigned short* __restrict__ Bt,
                                              unsigned short* __restrict__ C,
                                              const float* __restrict__ dinv,
                                              const int* __restrict__ flags, int useflag,
                                              int M) {
    __shared__ unsigned short smem[16384];   // 32 KB: B dbuf 2x16KB, then C 64x256 tile
    int tid  = threadIdx.x;
    int lane = tid & 63;
    int wave = tid >> 6;
    int q = lane >> 4;
    int r = lane & 15;
    int rowBase0 = blockIdx.x * 64;
    int rowBase = rowBase0 + wave * 16;
    int af32 = useflag ? flags[0] : 0;       // wave-uniform branch

    int arow = rowBase + r;
    arow = arow < M ? arow : M - 1;
    const unsigned short* aptrh = (const unsigned short*)Araw + (size_t)arow * 256;
    const float*          aptrf = (const float*)Araw + (size_t)arow * 256;

    auto stage = [&](int buf, int kk) {
#pragma unroll
        for (int j = 0; j < 4; ++j) {
            int c = wave * 256 + j * 64 + lane;
            int col = c >> 2;
            int kc = (c & 3) ^ (col & 3);
            const unsigned short* src = Bt + col * 256 + kk + kc * 8;
            unsigned short* dst = smem + buf * 8192 + (wave * 4 + j) * 512;
            __builtin_amdgcn_global_load_lds((gu32*)src, (lu32*)dst, 16, 0, 0);
        }
    };

    stage(0, 0);
    __syncthreads();                         // vmcnt(0) drain: buf0 ready

    f32x4 acc[16] = {};
    int cur = 0;
    for (int kk = 0; kk < 256; kk += 32) {
        if (kk < 224) stage(cur ^ 1, kk + 32);   // prefetch next slice first (T3)
        bf16x8 a;
        if (af32) {
            float4 v0 = *(const float4*)(aptrf + kk + q * 8);
            float4 v1 = *(const float4*)(aptrf + kk + q * 8 + 4);
            union { unsigned short s[8]; bf16x8 v; } ua;
            ua.s[0] = f2bf(v0.x); ua.s[1] = f2bf(v0.y); ua.s[2] = f2bf(v0.z); ua.s[3] = f2bf(v0.w);
            ua.s[4] = f2bf(v1.x); ua.s[5] = f2bf(v1.y); ua.s[6] = f2bf(v1.z); ua.s[7] = f2bf(v1.w);
            a = ua.v;
        } else {
            a = *(const bf16x8*)(aptrh + kk + q * 8);
        }
#pragma unroll
        for (int nt = 0; nt < 16; ++nt) {
            int col = nt * 16 + r;
            const unsigned short* bp = smem + cur * 8192 + col * 32 + (q ^ (col & 3)) * 8;
            bf16x8 b = *(const bf16x8*)bp;
            acc[nt] = __builtin_amdgcn_mfma_f32_16x16x32_bf16(a, b, acc[nt], 0, 0, 0);
        }
        __syncthreads();                     // drains next-slice loads; guards buf reuse
        cur ^= 1;
    }

    // epilogue: reuse smem as 64x256 bf16 C tile
    float ds4[4];
#pragma unroll
    for (int r2 = 0; r2 < 4; ++r2) {
        int row = rowBase + q * 4 + r2;
        ds4[r2] = (row < M) ? dinv[row] : 0.f;
    }
    int lrow0 = wave * 16 + q * 4;
#pragma unroll
    for (int nt = 0; nt < 16; ++nt) {
        int col = nt * 16 + r;
#pragma unroll
        for (int r2 = 0; r2 < 4; ++r2)
            smem[(lrow0 + r2) * 256 + col] = f2bf(acc[nt][r2] * ds4[r2]);
    }
    __syncthreads();
#pragma unroll
    for (int p = 0; p < 8; ++p) {
        int idx = wave * 4096 + p * 512 + lane * 8;   // in shorts
        int grow = rowBase0 + (idx >> 8);
        if (grow < M)
            *(uint4*)(C + (size_t)grow * 256 + (idx & 255)) = *(const uint4*)(smem + idx);
    }
}

// Pure row-sum aggregation over dinv-prescaled rows XWs (edge lists sorted by
// src range -> soft phasing). One wave per node; lane owns 8 channels (uint4);
// lane-half (0/1) takes even/odd edges, x4 unroll = 8 edges in flight.
// out[v] = dinv[v] * (sum_e XWs[src_e] + XWs[v]) + b
__global__ __launch_bounds__(256) void k_agg(const unsigned short* __restrict__ XWs,
                                             const int* __restrict__ csr,
                                             const int* __restrict__ offs,
                                             const float* __restrict__ dinv,
                                             const void* __restrict__ bias,
                                             void* __restrict__ out,
                                             int relu, int final_, const int* __restrict__ flags,
                                             int N) {
    int v = blockIdx.x * 4 + (threadIdx.x >> 6);
    if (v >= N) return;
    int lane = threadIdx.x & 63;
    int half = lane >> 5;            // 0 or 1
    int cl   = (lane & 31) * 8;      // 8 channels, 16 B
    float acc[8] = {};
    int beg = offs[v], end = offs[v + 1];
    int e = beg;
    for (; e + 8 <= end; e += 8) {
        int s[4]; uint4 u[4];
#pragma unroll
        for (int j = 0; j < 4; ++j) s[j] = csr[e + 2 * j + half];
#pragma unroll
        for (int j = 0; j < 4; ++j) u[j] = *(const uint4*)(XWs + (size_t)s[j] * 256 + cl);
#pragma unroll
        for (int j = 0; j < 4; ++j) {
            acc[0] += bflo(u[j].x); acc[1] += bfhi(u[j].x);
            acc[2] += bflo(u[j].y); acc[3] += bfhi(u[j].y);
            acc[4] += bflo(u[j].z); acc[5] += bfhi(u[j].z);
            acc[6] += bflo(u[j].w); acc[7] += bfhi(u[j].w);
        }
    }
    for (; e + 2 <= end; e += 2) {
        int s = csr[e + half];
        uint4 u = *(const uint4*)(XWs + (size_t)s * 256 + cl);
        acc[0] += bflo(u.x); acc[1] += bfhi(u.x);
        acc[2] += bflo(u.y); acc[3] += bfhi(u.y);
        acc[4] += bflo(u.z); acc[5] += bfhi(u.z);
        acc[6] += bflo(u.w); acc[7] += bfhi(u.w);
    }
    if (e < end && half == 0) {
        int s = csr[e];
        uint4 u = *(const uint4*)(XWs + (size_t)s * 256 + cl);
        acc[0] += bflo(u.x); acc[1] += bfhi(u.x);
        acc[2] += bflo(u.y); acc[3] += bfhi(u.y);
        acc[4] += bflo(u.z); acc[5] += bfhi(u.z);
        acc[6] += bflo(u.w); acc[7] += bfhi(u.w);
    }
#pragma unroll
    for (int k = 0; k < 8; ++k) acc[k] += __shfl_xor(acc[k], 32);
    if (half) return;                // lanes 0..31 finish the row

    float dv = dinv[v];
    uint4 su = *(const uint4*)(XWs + (size_t)v * 256 + cl);   // self (prescaled)
    float sf[8];
    sf[0] = bflo(su.x); sf[1] = bfhi(su.x);
    sf[2] = bflo(su.y); sf[3] = bfhi(su.y);
    sf[4] = bflo(su.z); sf[5] = bfhi(su.z);
    sf[6] = bflo(su.w); sf[7] = bfhi(su.w);
    float bb[8];
    if (flags[0]) {
        const float4* bp = (const float4*)((const float*)bias + cl);
        float4 b0 = bp[0], b1 = bp[1];
        bb[0] = b0.x; bb[1] = b0.y; bb[2] = b0.z; bb[3] = b0.w;
        bb[4] = b1.x; bb[5] = b1.y; bb[6] = b1.z; bb[7] = b1.w;
    } else {
        uint4 bu = *(const uint4*)((const unsigned short*)bias + cl);
        bb[0] = bflo(bu.x); bb[1] = bfhi(bu.x);
        bb[2] = bflo(bu.y); bb[3] = bfhi(bu.y);
        bb[4] = bflo(bu.z); bb[5] = bfhi(bu.z);
        bb[6] = bflo(bu.w); bb[7] = bfhi(bu.w);
    }
    float r[8];
#pragma unroll
    for (int k = 0; k < 8; ++k) {
        float t = dv * (acc[k] + sf[k]) + bb[k];
        r[k] = relu ? fmaxf(t, 0.f) : t;
    }
    if (final_ && flags[0]) {
        float* op = (float*)out + (size_t)v * 256 + cl;
        float4 o0, o1;
        o0.x = r[0]; o0.y = r[1]; o0.z = r[2]; o0.w = r[3];
        o1.x = r[4]; o1.y = r[5]; o1.z = r[6]; o1.w = r[7];
        ((float4*)op)[0] = o0; ((float4*)op)[1] = o1;
    } else {
        uint4 o;
        o.x = (unsigned)f2bf(r[0]) | ((unsigned)f2bf(r[1]) << 16);
        o.y = (unsigned)f2bf(r[2]) | ((unsigned)f2bf(r[3]) << 16);
        o.z = (unsigned)f2bf(r[4]) | ((unsigned)f2bf(r[5]) << 16);
        o.w = (unsigned)f2bf(r[6]) | ((unsigned)f2bf(r[7]) << 16);
        *(uint4*)((unsigned short*)out + (size_t)v * 256 + cl) = o;
    }
}

extern "C" void kernel_launch(void* const* d_in, const int* in_sizes, int n_in,
                              void* d_out, int out_size, void* d_ws, size_t ws_size,
                              hipStream_t stream) {
    (void)n_in; (void)out_size; (void)ws_size;
    const void* x  = d_in[0];
    const int*  ei = (const int*)d_in[1];
    const void* W1 = d_in[2];
    const void* b1 = d_in[3];
    const void* W2 = d_in[4];
    const void* b2 = d_in[5];

    int N = in_sizes[0] / 256;          // 50000
    int E = in_sizes[1] / 2;            // 1600000
    int NB = (N + BSZ - 1) / BSZ;       // 391 buckets of 128 nodes

    char* p = (char*)d_ws;
    auto alloc = [&](size_t bytes) {
        char* r = p;
        p += (bytes + 255) & ~(size_t)255;
        return r;
    };
    int*            flags  = (int*)alloc(8);
    int*            boff   = (int*)alloc(516 * 4);
    int*            offs   = (int*)alloc(((size_t)N + 1) * 4);
    float*          dinv   = (float*)alloc((size_t)N * 4);
    unsigned short* wt1    = (unsigned short*)alloc(256 * 256 * 2);
    unsigned short* wt2    = (unsigned short*)alloc(256 * 256 * 2);
    int*            csr    = (int*)alloc((size_t)E * 4);
    unsigned short* buf0   = (unsigned short*)alloc((size_t)N * 256 * 2);
    unsigned short* buf1   = (unsigned short*)alloc((size_t)N * 256 * 2);
    unsigned*       tmp    = (unsigned*)buf1;   // dead until gemm2 writes buf1
    int*            cmat   = (int*)buf0;        // dead until k_agg1 writes buf0
    unsigned short* xw1    = (unsigned short*)d_out;  // layer-1 XW scratch in d_out

    k_flags<<<1, 64, 0, stream>>>((const unsigned*)x, ei, E, flags);
    k_cmat<<<NBLK, 256, 0, stream>>>(ei, E, flags, cmat, NB);
    k_cscan<<<1, 512, 0, stream>>>(cmat, boff, offs, NB, N, E);
    k_fillmat<<<NBLK, 256, 0, stream>>>(ei, E, flags, cmat, tmp, NB);
    k_bbuild<<<NB, 256, 0, stream>>>(tmp, boff, offs, dinv, csr, N);

    k_cvtT<<<512, 256, 0, stream>>>(W1, wt1, W2, wt2, flags);

    int gAgg = (N + 3) / 4;
    k_gemm<<<(N + 63) / 64, 256, 0, stream>>>(x, wt1, xw1, dinv, flags, 1, N);   // dinv*(X@W1)
    k_agg<<<gAgg, 256, 0, stream>>>(xw1, csr, offs, dinv, b1,
                                    (void*)buf0, 1, 0, flags, N);                // h -> buf0
    k_gemm<<<(N + 63) / 64, 256, 0, stream>>>(buf0, wt2, buf1, dinv, flags, 0, N); // dinv*(H@W2)
    k_agg<<<gAgg, 256, 0, stream>>>(buf1, csr, offs, dinv, b2,
                                    d_out, 0, 1, flags, N);                      // final
}

// Round 9
// 401.747 us; speedup vs baseline: 1.7971x; 1.1734x over previous
//
#include <hip/hip_runtime.h>
#include <stdint.h>

typedef __attribute__((ext_vector_type(8))) short bf16x8;   // 8 bf16 = 4 VGPRs
typedef __attribute__((ext_vector_type(4))) float f32x4;

#define NBLK 256            // edge-chunk blocks for the deterministic counting sort
#define BSH  7              // bucket = 128 nodes
#define BSZ  128

typedef __attribute__((address_space(1))) const unsigned int gu32;
typedef __attribute__((address_space(3))) unsigned int lu32;

__device__ __forceinline__ float bf2f(unsigned short b) {
    union { unsigned u; float f; } c; c.u = ((unsigned)b) << 16; return c.f;
}
__device__ __forceinline__ float bflo(unsigned w) {
    union { unsigned u; float f; } c; c.u = w << 16; return c.f;
}
__device__ __forceinline__ float bfhi(unsigned w) {
    union { unsigned u; float f; } c; c.u = w & 0xffff0000u; return c.f;
}
__device__ __forceinline__ unsigned short f2bf(float f) {
    union { float f; unsigned u; } c; c.f = f;
    unsigned u = c.u;
    u += 0x7fffu + ((u >> 16) & 1u);          // round-to-nearest-even
    return (unsigned short)(u >> 16);
}

__global__ void GNNEncoder_317827579954_kernel() {}

// Fused prep: blocks [0,512) transpose/convert W1,W2 -> bf16 Wt; blocks [512,512+NBLK)
// compute the per-chunk bucket histogram (cmat column). Flags are computed
// block-locally (cheap) and persisted once for downstream kernels.
__global__ __launch_bounds__(256) void k_prep(const void* __restrict__ Wa,
                                              unsigned short* __restrict__ Wta,
                                              const void* __restrict__ Wb,
                                              unsigned short* __restrict__ Wtb,
                                              const unsigned* __restrict__ x,
                                              const int* __restrict__ ei, int E,
                                              int* __restrict__ cmat, int nb,
                                              int* __restrict__ flags) {
    __shared__ int lc[512];
    __shared__ int sflag;
    int t = threadIdx.x;
    int bb = blockIdx.x;
    if (bb < 512) {
        // ---- cvtT part: needs f32-vs-bf16 flag of dense inputs ----
        if (t < 64) {
            int pl = 0;
            for (int i = t; i < 256; i += 64) {
                unsigned u = x[i] & 0xffffu;
                unsigned e2 = (u >> 7) & 0xffu;
                if ((e2 >= 100u && e2 <= 145u) || u == 0u) ++pl;
            }
            for (int off = 32; off; off >>= 1) pl += __shfl_down(pl, off);
            if (t == 0) sflag = (pl >= 192) ? 0 : 1;     // 1 = f32
        }
        __syncthreads();
        int af32 = sflag;
        if (bb == 0 && t == 0) flags[0] = af32;
        const void* W = bb < 256 ? Wa : Wb;
        unsigned short* Wt = bb < 256 ? Wta : Wtb;
        int n = bb & 255;
        unsigned short v;
        if (af32) v = f2bf(((const float*)W)[t * 256 + n]);
        else      v = ((const unsigned short*)W)[t * 256 + n];
        Wt[n * 256 + t] = v;
    } else {
        // ---- cmat part: needs int64-vs-int32 flag of edge_index ----
        int b = bb - 512;
        if (t < 64) {
            int n = E < 64 ? E : 64;
            unsigned long long nz = __ballot(t < n ? (ei[2 * t + 1] != 0) : 0);
            if (t == 0) sflag = (nz == 0ull) ? 1 : 0;    // 1 = int64
        }
        for (int i = t; i < nb; i += 256) lc[i] = 0;
        __syncthreads();
        int i64 = sflag;
        if (b == 0 && t == 0) flags[1] = i64;
        int chunk = (E + NBLK - 1) / NBLK;
        int beg = b * chunk;
        int end = beg + chunk; if (end > E) end = E;
        for (int i = beg + t; i < end; i += 256) {
            int d = i64 ? ei[2 * E + 2 * i] : ei[E + i];
            atomicAdd(&lc[d >> BSH], 1);
        }
        __syncthreads();
        for (int j = t; j < nb; j += 256) cmat[j * NBLK + b] = lc[j];
    }
}

// Per-bucket-row exclusive scan of cmat (in place) + row total. Fully parallel
// (replaces the serial single-block k_cscan loop).
__global__ __launch_bounds__(256) void k_rowscan(int* __restrict__ cmat,
                                                 int* __restrict__ btot) {
    __shared__ int sc[256];
    int j = blockIdx.x;
    int t = threadIdx.x;
    int* row = cmat + j * NBLK;
    int v = row[t];
    sc[t] = v;
    __syncthreads();
    for (int off = 1; off < 256; off <<= 1) {
        int u = (t >= off) ? sc[t - off] : 0;
        __syncthreads();
        sc[t] += u;
        __syncthreads();
    }
    row[t] = sc[t] - v;                  // exclusive prefix within row
    if (t == 255) btot[j] = sc[255];     // bucket total
}

// One small block: exclusive scan of bucket totals -> boff.
__global__ __launch_bounds__(512) void k_bscan(const int* __restrict__ btot,
                                               int* __restrict__ boff,
                                               int* __restrict__ offs,
                                               int nb, int N, int E) {
    __shared__ int sc[512];
    int t = threadIdx.x;
    int v = (t < nb) ? btot[t] : 0;
    sc[t] = v;
    __syncthreads();
    for (int off = 1; off < 512; off <<= 1) {
        int u = (t >= off) ? sc[t - off] : 0;
        __syncthreads();
        sc[t] += u;
        __syncthreads();
    }
    if (t < nb) boff[t] = sc[t] - v;
    if (t == 0) { boff[nb] = E; offs[N] = E; }
}

__global__ __launch_bounds__(256) void k_fillmat(const int* __restrict__ ei, int E,
                                                 const int* __restrict__ flags,
                                                 const int* __restrict__ cmat,
                                                 const int* __restrict__ boff,
                                                 unsigned* __restrict__ tmp, int nb) {
    __shared__ int cur[512];
    int t = threadIdx.x, b = blockIdx.x;
    for (int j = t; j < nb; j += 256) cur[j] = cmat[j * NBLK + b] + boff[j];
    __syncthreads();
    int chunk = (E + NBLK - 1) / NBLK;
    int beg = b * chunk;
    int end = beg + chunk; if (end > E) end = E;
    int i64 = flags[1];
    for (int i = beg + t; i < end; i += 256) {
        int s, d;
        if (i64) { s = ei[2 * i]; d = ei[2 * E + 2 * i]; }
        else     { s = ei[i];     d = ei[E + i]; }
        int p = atomicAdd(&cur[d >> BSH], 1);        // LDS atomic only
        tmp[p] = ((unsigned)s << BSH) | (unsigned)(d & (BSZ - 1));
    }
}

// Per-bucket: LDS (node, src-range) key count + scan -> offs, dinv, then key-sorted
// CSR fill (node-major, src-range-minor ordering).
__global__ __launch_bounds__(256) void k_bbuild(const unsigned* __restrict__ tmp,
                                                const int* __restrict__ boff,
                                                int* __restrict__ offs,
                                                float* __restrict__ dinv,
                                                int* __restrict__ csr, int N) {
    __shared__ int kc[2048];
    __shared__ int cur[2048];
    __shared__ int sc[256];
    __shared__ int tot;
    int b = blockIdx.x;
    int t = threadIdx.x;
    int base = b << BSH;
    int beg = boff[b], end = boff[b + 1];
    for (int i = t; i < 2048; i += 256) kc[i] = 0;
    __syncthreads();
    for (int i = beg + t; i < end; i += 256) {
        unsigned u = tmp[i];
        atomicAdd(&kc[(u & 127u) * 16 + (u >> 19)], 1);   // u>>19 = src>>12
    }
    __syncthreads();
    int b8 = t * 8, loc[8], msum = 0;
#pragma unroll
    for (int j = 0; j < 8; ++j) { loc[j] = kc[b8 + j]; msum += loc[j]; }
    sc[t] = msum;
    __syncthreads();
    int val = msum;
    for (int off = 1; off < 256; off <<= 1) {
        int u2 = (t >= off) ? sc[t - off] : 0;
        __syncthreads();
        sc[t] += u2;
        __syncthreads();
    }
    int run = sc[t] - val;
    if (t == 255) tot = sc[255];
#pragma unroll
    for (int j = 0; j < 8; ++j) { int v2 = loc[j]; kc[b8 + j] = run; cur[b8 + j] = run; run += v2; }
    __syncthreads();
    if (t < 128) {
        int v = base + t;
        if (v < N) {
            int s0 = kc[t * 16];
            int s1 = (t == 127) ? tot : kc[(t + 1) * 16];
            offs[v] = beg + s0;
            dinv[v] = rsqrtf((float)(s1 - s0 + 1));   // +1 = self loop
        }
    }
    __syncthreads();
    for (int i = beg + t; i < end; i += 256) {
        unsigned u = tmp[i];
        int p = atomicAdd(&cur[(u & 127u) * 16 + (u >> 19)], 1);
        csr[beg + p] = (int)(u >> BSH);
    }
}

// C[M,256] = dinv[row] * (A[M,256] @ Bt^T), A in f32 (converted in-flight) or bf16.
// B K-slices double-buffered in LDS via global_load_lds (16 B, XOR-swizzled chunks);
// C staged through the same LDS for fully-coalesced uint4 stores.
__global__ __launch_bounds__(256) void k_gemm(const void* __restrict__ Araw,
                                              const unsigned short* __restrict__ Bt,
                                              unsigned short* __restrict__ C,
                                              const float* __restrict__ dinv,
                                              const int* __restrict__ flags, int useflag,
                                              int M) {
    __shared__ unsigned short smem[16384];   // 32 KB: B dbuf 2x16KB, then C 64x256 tile
    int tid  = threadIdx.x;
    int lane = tid & 63;
    int wave = tid >> 6;
    int q = lane >> 4;
    int r = lane & 15;
    int rowBase0 = blockIdx.x * 64;
    int rowBase = rowBase0 + wave * 16;
    int af32 = useflag ? flags[0] : 0;       // wave-uniform branch

    int arow = rowBase + r;
    arow = arow < M ? arow : M - 1;
    const unsigned short* aptrh = (const unsigned short*)Araw + (size_t)arow * 256;
    const float*          aptrf = (const float*)Araw + (size_t)arow * 256;

    auto stage = [&](int buf, int kk) {
#pragma unroll
        for (int j = 0; j < 4; ++j) {
            int c = wave * 256 + j * 64 + lane;
            int col = c >> 2;
            int kc = (c & 3) ^ (col & 3);
            const unsigned short* src = Bt + col * 256 + kk + kc * 8;
            unsigned short* dst = smem + buf * 8192 + (wave * 4 + j) * 512;
            __builtin_amdgcn_global_load_lds((gu32*)src, (lu32*)dst, 16, 0, 0);
        }
    };

    stage(0, 0);
    __syncthreads();                         // vmcnt(0) drain: buf0 ready

    f32x4 acc[16] = {};
    int cur = 0;
    for (int kk = 0; kk < 256; kk += 32) {
        if (kk < 224) stage(cur ^ 1, kk + 32);   // prefetch next slice first (T3)
        bf16x8 a;
        if (af32) {
            float4 v0 = *(const float4*)(aptrf + kk + q * 8);
            float4 v1 = *(const float4*)(aptrf + kk + q * 8 + 4);
            union { unsigned short s[8]; bf16x8 v; } ua;
            ua.s[0] = f2bf(v0.x); ua.s[1] = f2bf(v0.y); ua.s[2] = f2bf(v0.z); ua.s[3] = f2bf(v0.w);
            ua.s[4] = f2bf(v1.x); ua.s[5] = f2bf(v1.y); ua.s[6] = f2bf(v1.z); ua.s[7] = f2bf(v1.w);
            a = ua.v;
        } else {
            a = *(const bf16x8*)(aptrh + kk + q * 8);
        }
#pragma unroll
        for (int nt = 0; nt < 16; ++nt) {
            int col = nt * 16 + r;
            const unsigned short* bp = smem + cur * 8192 + col * 32 + (q ^ (col & 3)) * 8;
            bf16x8 b = *(const bf16x8*)bp;
            acc[nt] = __builtin_amdgcn_mfma_f32_16x16x32_bf16(a, b, acc[nt], 0, 0, 0);
        }
        __syncthreads();                     // drains next-slice loads; guards buf reuse
        cur ^= 1;
    }

    // epilogue: reuse smem as 64x256 bf16 C tile
    float ds4[4];
#pragma unroll
    for (int r2 = 0; r2 < 4; ++r2) {
        int row = rowBase + q * 4 + r2;
        ds4[r2] = (row < M) ? dinv[row] : 0.f;
    }
    int lrow0 = wave * 16 + q * 4;
#pragma unroll
    for (int nt = 0; nt < 16; ++nt) {
        int col = nt * 16 + r;
#pragma unroll
        for (int r2 = 0; r2 < 4; ++r2)
            smem[(lrow0 + r2) * 256 + col] = f2bf(acc[nt][r2] * ds4[r2]);
    }
    __syncthreads();
#pragma unroll
    for (int p = 0; p < 8; ++p) {
        int idx = wave * 4096 + p * 512 + lane * 8;   // in shorts
        int grow = rowBase0 + (idx >> 8);
        if (grow < M)
            *(uint4*)(C + (size_t)grow * 256 + (idx & 255)) = *(const uint4*)(smem + idx);
    }
}

// Pure row-sum aggregation over dinv-prescaled rows XWs. One wave per node;
// lane owns 8 channels (uint4); lane-half (0/1) takes even/odd edges, x4 unroll
// = 8 edges in flight.  out[v] = dinv[v] * (sum_e XWs[src_e] + XWs[v]) + b
__global__ __launch_bounds__(256) void k_agg(const unsigned short* __restrict__ XWs,
                                             const int* __restrict__ csr,
                                             const int* __restrict__ offs,
                                             const float* __restrict__ dinv,
                                             const void* __restrict__ bias,
                                             void* __restrict__ out,
                                             int relu, int final_, const int* __restrict__ flags,
                                             int N) {
    int v = blockIdx.x * 4 + (threadIdx.x >> 6);
    if (v >= N) return;
    int lane = threadIdx.x & 63;
    int half = lane >> 5;            // 0 or 1
    int cl   = (lane & 31) * 8;      // 8 channels, 16 B
    float acc[8] = {};
    int beg = offs[v], end = offs[v + 1];
    int e = beg;
    for (; e + 8 <= end; e += 8) {
        int s[4]; uint4 u[4];
#pragma unroll
        for (int j = 0; j < 4; ++j) s[j] = csr[e + 2 * j + half];
#pragma unroll
        for (int j = 0; j < 4; ++j) u[j] = *(const uint4*)(XWs + (size_t)s[j] * 256 + cl);
#pragma unroll
        for (int j = 0; j < 4; ++j) {
            acc[0] += bflo(u[j].x); acc[1] += bfhi(u[j].x);
            acc[2] += bflo(u[j].y); acc[3] += bfhi(u[j].y);
            acc[4] += bflo(u[j].z); acc[5] += bfhi(u[j].z);
            acc[6] += bflo(u[j].w); acc[7] += bfhi(u[j].w);
        }
    }
    for (; e + 2 <= end; e += 2) {
        int s = csr[e + half];
        uint4 u = *(const uint4*)(XWs + (size_t)s * 256 + cl);
        acc[0] += bflo(u.x); acc[1] += bfhi(u.x);
        acc[2] += bflo(u.y); acc[3] += bfhi(u.y);
        acc[4] += bflo(u.z); acc[5] += bfhi(u.z);
        acc[6] += bflo(u.w); acc[7] += bfhi(u.w);
    }
    if (e < end && half == 0) {
        int s = csr[e];
        uint4 u = *(const uint4*)(XWs + (size_t)s * 256 + cl);
        acc[0] += bflo(u.x); acc[1] += bfhi(u.x);
        acc[2] += bflo(u.y); acc[3] += bfhi(u.y);
        acc[4] += bflo(u.z); acc[5] += bfhi(u.z);
        acc[6] += bflo(u.w); acc[7] += bfhi(u.w);
    }
#pragma unroll
    for (int k = 0; k < 8; ++k) acc[k] += __shfl_xor(acc[k], 32);
    if (half) return;                // lanes 0..31 finish the row

    float dv = dinv[v];
    uint4 su = *(const uint4*)(XWs + (size_t)v * 256 + cl);   // self (prescaled)
    float sf[8];
    sf[0] = bflo(su.x); sf[1] = bfhi(su.x);
    sf[2] = bflo(su.y); sf[3] = bfhi(su.y);
    sf[4] = bflo(su.z); sf[5] = bfhi(su.z);
    sf[6] = bflo(su.w); sf[7] = bfhi(su.w);
    float bb[8];
    if (flags[0]) {
        const float4* bp = (const float4*)((const float*)bias + cl);
        float4 b0 = bp[0], b1 = bp[1];
        bb[0] = b0.x; bb[1] = b0.y; bb[2] = b0.z; bb[3] = b0.w;
        bb[4] = b1.x; bb[5] = b1.y; bb[6] = b1.z; bb[7] = b1.w;
    } else {
        uint4 bu = *(const uint4*)((const unsigned short*)bias + cl);
        bb[0] = bflo(bu.x); bb[1] = bfhi(bu.x);
        bb[2] = bflo(bu.y); bb[3] = bfhi(bu.y);
        bb[4] = bflo(bu.z); bb[5] = bfhi(bu.z);
        bb[6] = bflo(bu.w); bb[7] = bfhi(bu.w);
    }
    float r[8];
#pragma unroll
    for (int k = 0; k < 8; ++k) {
        float t = dv * (acc[k] + sf[k]) + bb[k];
        r[k] = relu ? fmaxf(t, 0.f) : t;
    }
    if (final_ && flags[0]) {
        float* op = (float*)out + (size_t)v * 256 + cl;
        float4 o0, o1;
        o0.x = r[0]; o0.y = r[1]; o0.z = r[2]; o0.w = r[3];
        o1.x = r[4]; o1.y = r[5]; o1.z = r[6]; o1.w = r[7];
        ((float4*)op)[0] = o0; ((float4*)op)[1] = o1;
    } else {
        uint4 o;
        o.x = (unsigned)f2bf(r[0]) | ((unsigned)f2bf(r[1]) << 16);
        o.y = (unsigned)f2bf(r[2]) | ((unsigned)f2bf(r[3]) << 16);
        o.z = (unsigned)f2bf(r[4]) | ((unsigned)f2bf(r[5]) << 16);
        o.w = (unsigned)f2bf(r[6]) | ((unsigned)f2bf(r[7]) << 16);
        *(uint4*)((unsigned short*)out + (size_t)v * 256 + cl) = o;
    }
}

extern "C" void kernel_launch(void* const* d_in, const int* in_sizes, int n_in,
                              void* d_out, int out_size, void* d_ws, size_t ws_size,
                              hipStream_t stream) {
    (void)n_in; (void)out_size; (void)ws_size;
    const void* x  = d_in[0];
    const int*  ei = (const int*)d_in[1];
    const void* W1 = d_in[2];
    const void* b1 = d_in[3];
    const void* W2 = d_in[4];
    const void* b2 = d_in[5];

    int N = in_sizes[0] / 256;          // 50000
    int E = in_sizes[1] / 2;            // 1600000
    int NB = (N + BSZ - 1) / BSZ;       // 391 buckets of 128 nodes

    char* p = (char*)d_ws;
    auto alloc = [&](size_t bytes) {
        char* r = p;
        p += (bytes + 255) & ~(size_t)255;
        return r;
    };
    int*            flags  = (int*)alloc(8);
    int*            boff   = (int*)alloc(516 * 4);
    int*            btot   = (int*)alloc(512 * 4);
    int*            offs   = (int*)alloc(((size_t)N + 1) * 4);
    float*          dinv   = (float*)alloc((size_t)N * 4);
    unsigned short* wt1    = (unsigned short*)alloc(256 * 256 * 2);
    unsigned short* wt2    = (unsigned short*)alloc(256 * 256 * 2);
    int*            csr    = (int*)alloc((size_t)E * 4);
    unsigned short* buf0   = (unsigned short*)alloc((size_t)N * 256 * 2);
    unsigned short* buf1   = (unsigned short*)alloc((size_t)N * 256 * 2);
    unsigned*       tmp    = (unsigned*)buf1;   // dead until gemm2 writes buf1
    int*            cmat   = (int*)buf0;        // dead until k_agg1 writes buf0
    unsigned short* xw1    = (unsigned short*)d_out;  // layer-1 XW scratch in d_out

    k_prep<<<512 + NBLK, 256, 0, stream>>>(W1, wt1, W2, wt2,
                                           (const unsigned*)x, ei, E, cmat, NB, flags);
    k_rowscan<<<NB, 256, 0, stream>>>(cmat, btot);
    k_bscan<<<1, 512, 0, stream>>>(btot, boff, offs, NB, N, E);
    k_fillmat<<<NBLK, 256, 0, stream>>>(ei, E, flags, cmat, boff, tmp, NB);
    k_bbuild<<<NB, 256, 0, stream>>>(tmp, boff, offs, dinv, csr, N);

    int gAgg = (N + 3) / 4;
    k_gemm<<<(N + 63) / 64, 256, 0, stream>>>(x, wt1, xw1, dinv, flags, 1, N);   // dinv*(X@W1)
    k_agg<<<gAgg, 256, 0, stream>>>(xw1, csr, offs, dinv, b1,
                                    (void*)buf0, 1, 0, flags, N);                // h -> buf0
    k_gemm<<<(N + 63) / 64, 256, 0, stream>>>(buf0, wt2, buf1, dinv, flags, 0, N); // dinv*(H@W2)
    k_agg<<<gAgg, 256, 0, stream>>>(buf1, csr, offs, dinv, b2,
                                    d_out, 0, 1, flags, N);                      // final
}